// Round 3
// baseline (36.871 us; speedup 1.0000x reference)
//
#include <hip/hip_runtime.h>
#include <hip/hip_bf16.h>

#define N_ROBOTS 2048
#define EMBED 256
#define M_GROUPS 4096
#define GROUP_K 16
#define N_OBS 64
#define OUT_W 518   // 256 + 256 + 1 + 3 + 1 + 1

// ws layout (floats) — every slot fully rewritten every launch (replay-safe):
//   [0, 2048)     rowsum_rr[r]  = sum_n attn_rr[r, n]
//   [2048, 4096)  rowsum_ro[r]  = sum_o attn_ro[r, o]
//   [4096, 4352)  hglob_sum[c]  = sum_r h[r, c]

__global__ __launch_bounds__(256) void precompute_kernel(
    const float* __restrict__ h,
    const float* __restrict__ attn_rr,
    const float* __restrict__ attn_ro,
    float* __restrict__ ws)
{
    const int b = blockIdx.x;
    const int t = threadIdx.x;

    if (b < N_ROBOTS) {
        // rowsum of attn_rr row b (2048 floats) and attn_ro row b (64 floats)
        const float* row = attn_rr + (size_t)b * N_ROBOTS;
        float s = 0.f;
        #pragma unroll
        for (int i = 0; i < N_ROBOTS / 256; ++i) s += row[t + 256 * i];

        float so = 0.f;
        if (t < N_OBS) so = attn_ro[b * N_OBS + t];

        #pragma unroll
        for (int off = 32; off > 0; off >>= 1) {
            s  += __shfl_down(s,  off);
            so += __shfl_down(so, off);
        }
        __shared__ float lds[8];
        const int wave = t >> 6, lane = t & 63;
        if (lane == 0) { lds[wave] = s; lds[4 + wave] = so; }
        __syncthreads();
        if (t == 0) {
            ws[b]            = lds[0] + lds[1] + lds[2] + lds[3];
            ws[N_ROBOTS + b] = lds[4] + lds[5] + lds[6] + lds[7];
        }
    } else {
        // h_glob column sums: 8 blocks x 32 columns each, no atomics
        const int bb   = b - N_ROBOTS;          // 0..7
        const int col  = bb * 32 + (t & 31);    // global column
        const int chnk = t >> 5;                // 0..7, 256 rows each
        float s = 0.f;
        const int r0 = chnk * (N_ROBOTS / 8);
        for (int r = r0; r < r0 + N_ROBOTS / 8; ++r)
            s += h[(size_t)r * EMBED + col];
        __shared__ float hg[8][32];
        hg[chnk][t & 31] = s;
        __syncthreads();
        if (t < 32) {
            float tot = 0.f;
            #pragma unroll
            for (int c = 0; c < 8; ++c) tot += hg[c][t];
            ws[2 * N_ROBOTS + bb * 32 + t] = tot;
        }
    }
}

__global__ __launch_bounds__(256) void group_kernel(
    const float* __restrict__ h,
    const float* __restrict__ attn_rr,
    const float* __restrict__ dist,
    const float* __restrict__ clr,
    const int*   __restrict__ groups,
    const float* __restrict__ ws,
    float* __restrict__ out)
{
    const int m = blockIdx.x;
    const int t = threadIdx.x;

    __shared__ int   g[GROUP_K];
    __shared__ int   uniq[GROUP_K];
    __shared__ float s16[4 * GROUP_K];   // rowsum_rr | rowsum_ro | dist | clr
    __shared__ float red0[256], red1[256], red2[256];

    if (t < GROUP_K) g[t] = groups[m * GROUP_K + t];
    __syncthreads();

    // h_g: thread t owns embedding column t, sums the 16 member rows
    float hsum = 0.f;
    #pragma unroll
    for (int k = 0; k < GROUP_K; ++k) hsum += h[(size_t)g[k] * EMBED + t];

    // 16x16 attn_rr pair block: thread t -> (i = t>>4, j = t&15)
    const int i = t >> 4, j = t & 15;
    const int gi = g[i], gj = g[j];
    const float v   = attn_rr[(size_t)gi * N_ROBOTS + gj];
    const float neq = (gi != gj) ? 1.f : 0.f;

    if (t < GROUP_K) {
        int u = 1;
        for (int p = 0; p < t; ++p) if (g[p] == g[t]) { u = 0; break; }
        uniq[t] = u;
        const int gt = g[t];
        s16[t]                = ws[gt];              // rowsum_rr
        s16[GROUP_K + t]      = ws[N_ROBOTS + gt];   // rowsum_ro
        s16[2 * GROUP_K + t]  = dist[gt];
        s16[3 * GROUP_K + t]  = clr[gt];
    }
    __syncthreads();

    red0[t] = v * neq;                 // a_in numerator
    red1[t] = neq;                     // cnt_in
    red2[t] = uniq[j] ? v : 0.f;       // sum over unique member columns
    __syncthreads();
    #pragma unroll
    for (int off = 128; off > 0; off >>= 1) {
        if (t < off) {
            red0[t] += red0[t + off];
            red1[t] += red1[t + off];
            red2[t] += red2[t + off];
        }
        __syncthreads();
    }

    // outputs: h_g (256) | h_glob (256) | size | a_in a_out a_obs | dist | clr
    const size_t base = (size_t)m * OUT_W;
    out[base + t]         = hsum * (1.f / GROUP_K);
    out[base + EMBED + t] = ws[2 * N_ROBOTS + t] * (1.f / N_ROBOTS);

    if (t == 0) {
        float rr = 0.f, ro = 0.f, ds = 0.f;
        float cm = s16[3 * GROUP_K];
        int ucnt = 0;
        #pragma unroll
        for (int k = 0; k < GROUP_K; ++k) {
            rr += s16[k];
            ro += s16[GROUP_K + k];
            ds += s16[2 * GROUP_K + k];
            cm  = fminf(cm, s16[3 * GROUP_K + k]);
            ucnt += uniq[k];
        }
        const float a_in    = red0[0] / fmaxf(red1[0], 1.f);
        const float n_out   = (float)(N_ROBOTS - ucnt);
        const float out_sum = rr - red2[0];
        const float a_out   = out_sum / fmaxf((float)GROUP_K * n_out, 1.f);
        const float a_obs   = ro * (1.f / (GROUP_K * N_OBS));

        out[base + 512] = (float)GROUP_K / 3.0f;
        out[base + 513] = a_in;
        out[base + 514] = a_out;
        out[base + 515] = a_obs;
        out[base + 516] = ds * (1.f / GROUP_K);
        out[base + 517] = cm;
    }
}

extern "C" void kernel_launch(void* const* d_in, const int* in_sizes, int n_in,
                              void* d_out, int out_size, void* d_ws, size_t ws_size,
                              hipStream_t stream) {
    const float* h       = (const float*)d_in[0];
    const float* attn_rr = (const float*)d_in[1];
    const float* attn_ro = (const float*)d_in[2];
    const float* dist    = (const float*)d_in[3];
    const float* clr     = (const float*)d_in[4];
    const int*   groups  = (const int*)d_in[5];
    float* out = (float*)d_out;
    float* ws  = (float*)d_ws;

    precompute_kernel<<<N_ROBOTS + 8, 256, 0, stream>>>(h, attn_rr, attn_ro, ws);
    group_kernel<<<M_GROUPS, 256, 0, stream>>>(h, attn_rr, dist, clr, groups, ws, out);
}

// Round 4
// 36.810 us; speedup vs baseline: 1.0016x; 1.0016x over previous
//
#include <hip/hip_runtime.h>
#include <hip/hip_bf16.h>

#define N_ROBOTS 2048
#define EMBED 256
#define M_GROUPS 4096
#define GROUP_K 16
#define N_OBS 64
#define OUT_W 518   // 256 + 256 + 1 + 3 + 1 + 1

// ws layout (floats) — every slot fully rewritten every launch (replay-safe):
//   [0, 2048)     rowsum_rr[r]  = sum_n attn_rr[r, n]
//   [2048, 4096)  rowsum_ro[r]  = sum_o attn_ro[r, o]
//   [4096, 4352)  hglob_sum[c]  = sum_r h[r, c]

__global__ __launch_bounds__(256) void precompute_kernel(
    const float* __restrict__ h,
    const float* __restrict__ attn_rr,
    const float* __restrict__ attn_ro,
    float* __restrict__ ws)
{
    const int b = blockIdx.x;
    const int t = threadIdx.x;

    if (b < N_ROBOTS) {
        // rowsum of attn_rr row b: 2048 floats = 512 float4; 256 threads x 2
        const float4* row4 = (const float4*)(attn_rr + (size_t)b * N_ROBOTS);
        const float4 a = row4[t];
        const float4 c = row4[t + 256];
        float s = (a.x + a.y) + (a.z + a.w) + (c.x + c.y) + (c.z + c.w);

        float so = (t < N_OBS) ? attn_ro[b * N_OBS + t] : 0.f;

        #pragma unroll
        for (int off = 32; off > 0; off >>= 1) {
            s  += __shfl_down(s,  off);
            so += __shfl_down(so, off);
        }
        __shared__ float lds[8];
        const int wave = t >> 6, lane = t & 63;
        if (lane == 0) { lds[wave] = s; lds[4 + wave] = so; }
        __syncthreads();
        if (t == 0) {
            ws[b]            = lds[0] + lds[1] + lds[2] + lds[3];
            ws[N_ROBOTS + b] = lds[4] + lds[5] + lds[6] + lds[7];
        }
    } else {
        // h_glob column sums: 8 blocks x 32 columns each, no atomics
        const int bb   = b - N_ROBOTS;          // 0..7
        const int col  = bb * 32 + (t & 31);    // global column
        const int chnk = t >> 5;                // 0..7, 256 rows each
        float s = 0.f;
        const int r0 = chnk * (N_ROBOTS / 8);
        for (int r = r0; r < r0 + N_ROBOTS / 8; ++r)
            s += h[(size_t)r * EMBED + col];
        __shared__ float hg[8][32];
        hg[chnk][t & 31] = s;
        __syncthreads();
        if (t < 32) {
            float tot = 0.f;
            #pragma unroll
            for (int c = 0; c < 8; ++c) tot += hg[c][t];
            ws[2 * N_ROBOTS + bb * 32 + t] = tot;
        }
    }
}

// One wave (64 lanes) per group: wave-synchronous, shuffle reductions only.
__global__ __launch_bounds__(64) void group_kernel(
    const float* __restrict__ h,
    const float* __restrict__ attn_rr,
    const float* __restrict__ dist,
    const float* __restrict__ clr,
    const int*   __restrict__ groups,
    const float* __restrict__ ws,
    float* __restrict__ out)
{
    const int m    = blockIdx.x;
    const int lane = threadIdx.x;   // 0..63

    __shared__ int   gl[GROUP_K];
    __shared__ float uql[GROUP_K];

    if (lane < GROUP_K) gl[lane] = groups[m * GROUP_K + lane];
    __syncthreads();

    if (lane < GROUP_K) {
        const int gt = gl[lane];
        float u = 1.f;
        for (int p = 0; p < lane; ++p) if (gl[p] == gt) { u = 0.f; break; }
        uql[lane] = u;
    }
    __syncthreads();

    // h_g: lane owns float2-columns lane and lane+64 (cols 2l,2l+1 / 2l+128,2l+129)
    float2 ha = {0.f, 0.f}, hb = {0.f, 0.f};
    #pragma unroll
    for (int k = 0; k < GROUP_K; ++k) {
        const float2* hr = (const float2*)(h + (size_t)gl[k] * EMBED);
        const float2 x = hr[lane];
        const float2 y = hr[lane + 64];
        ha.x += x.x; ha.y += x.y;
        hb.x += y.x; hb.y += y.y;
    }

    // 16x16 pair block: lane handles (i = (lane>>4)+4q, j = lane&15), q=0..3
    const int   j  = lane & 15;
    const int   gj = gl[j];
    const float uj = uql[j];
    float s_in = 0.f, s_cnt = 0.f, s_uq = 0.f;
    #pragma unroll
    for (int q = 0; q < 4; ++q) {
        const int gi = gl[(lane >> 4) + 4 * q];
        const float v = attn_rr[(size_t)gi * N_ROBOTS + gj];
        if (gi != gj) { s_in += v; s_cnt += 1.f; }
        s_uq += uj * v;
    }

    // per-member stats on lanes 0..15
    float m_rr = 0.f, m_ro = 0.f, m_ds = 0.f, m_cl = 1e30f, m_uq = 0.f;
    if (lane < GROUP_K) {
        const int gt = gl[lane];
        m_rr = ws[gt];
        m_ro = ws[N_ROBOTS + gt];
        m_ds = dist[gt];
        m_cl = clr[gt];
        m_uq = uql[lane];
    }
    #pragma unroll
    for (int off = 8; off > 0; off >>= 1) {
        m_rr += __shfl_down(m_rr, off);
        m_ro += __shfl_down(m_ro, off);
        m_ds += __shfl_down(m_ds, off);
        m_cl  = fminf(m_cl, __shfl_down(m_cl, off));
        m_uq += __shfl_down(m_uq, off);
    }
    #pragma unroll
    for (int off = 32; off > 0; off >>= 1) {
        s_in  += __shfl_down(s_in,  off);
        s_cnt += __shfl_down(s_cnt, off);
        s_uq  += __shfl_down(s_uq,  off);
    }

    // stores: h_g | h_glob | tails   (base is even -> float2-aligned)
    const size_t base = (size_t)m * OUT_W;
    float2* out2 = (float2*)(out + base);
    const float2* wg2 = (const float2*)(ws + 2 * N_ROBOTS);

    float2 r;
    r.x = ha.x * (1.f / GROUP_K); r.y = ha.y * (1.f / GROUP_K);
    out2[lane] = r;
    r.x = hb.x * (1.f / GROUP_K); r.y = hb.y * (1.f / GROUP_K);
    out2[lane + 64] = r;
    float2 g0 = wg2[lane], g1 = wg2[lane + 64];
    g0.x *= (1.f / N_ROBOTS); g0.y *= (1.f / N_ROBOTS);
    g1.x *= (1.f / N_ROBOTS); g1.y *= (1.f / N_ROBOTS);
    out2[lane + 128] = g0;
    out2[lane + 192] = g1;

    if (lane == 0) {
        const float a_in  = s_in / fmaxf(s_cnt, 1.f);
        const float n_out = (float)N_ROBOTS - m_uq;
        const float a_out = (m_rr - s_uq) / fmaxf((float)GROUP_K * n_out, 1.f);
        const float a_obs = m_ro * (1.f / (GROUP_K * N_OBS));
        out[base + 512] = (float)GROUP_K / 3.0f;
        out[base + 513] = a_in;
        out[base + 514] = a_out;
        out[base + 515] = a_obs;
        out[base + 516] = m_ds * (1.f / GROUP_K);
        out[base + 517] = m_cl;
    }
}

extern "C" void kernel_launch(void* const* d_in, const int* in_sizes, int n_in,
                              void* d_out, int out_size, void* d_ws, size_t ws_size,
                              hipStream_t stream) {
    const float* h       = (const float*)d_in[0];
    const float* attn_rr = (const float*)d_in[1];
    const float* attn_ro = (const float*)d_in[2];
    const float* dist    = (const float*)d_in[3];
    const float* clr     = (const float*)d_in[4];
    const int*   groups  = (const int*)d_in[5];
    float* out = (float*)d_out;
    float* ws  = (float*)d_ws;

    precompute_kernel<<<N_ROBOTS + 8, 256, 0, stream>>>(h, attn_rr, attn_ro, ws);
    group_kernel<<<M_GROUPS, 64, 0, stream>>>(h, attn_rr, dist, clr, groups, ws, out);
}